// Round 2
// baseline (485.582 us; speedup 1.0000x reference)
//
#include <hip/hip_runtime.h>
#include <math.h>

#define NNODES 50000
#define NEG_SLOPE 0.2f

typedef unsigned short ushort8v __attribute__((ext_vector_type(8)));
typedef unsigned short ushort4v __attribute__((ext_vector_type(4)));
typedef short short8v __attribute__((ext_vector_type(8)));
typedef float f32x4 __attribute__((ext_vector_type(4)));
typedef float f32x2 __attribute__((ext_vector_type(2)));

__device__ __forceinline__ unsigned short f2bf(float f){
    unsigned u = __float_as_uint(f);
    u += 0x7fff + ((u >> 16) & 1);   // RNE; inputs finite
    return (unsigned short)(u >> 16);
}

// ---------------- prep helpers ----------------
__device__ __forceinline__ void emit_wa(const float* __restrict__ W, const float* __restrict__ a_s,
                                        const float* __restrict__ a_d, unsigned short* __restrict__ Wt,
                                        int Kin, int C, int id){
    const int n = id / Kin, k = id - n * Kin;
    float v = 0.f;
    if(n < 8){
        const int hh = n & 3;
        const float* av = (n < 4) ? a_s : a_d;
        for(int c = 0; c < C; c++) v += W[(size_t)k * (4 * C) + hh * C + c] * av[hh * C + c];
    }
    Wt[id] = f2bf(v);
}

__device__ __forceinline__ void emit_wc(const float* __restrict__ W, unsigned short* __restrict__ Wt,
                                        int Kin, int C, int id){
    const int c = id / (4 * Kin);
    const int hk = id - c * (4 * Kin);
    const int h = hk / Kin, k = hk - h * Kin;
    const float v = (c < C) ? W[(size_t)k * (4 * C) + h * C + c] * 0.25f : 0.f;
    Wt[id] = f2bf(v);
}

// ---------------- init+prep: detect (block 0) + zero deg + xbf + Wa* + Wc* ----------------
__global__ void initprep_kernel(const unsigned long long* __restrict__ e, int* __restrict__ flag,
                                int* __restrict__ deg, int N,
                                const float* __restrict__ x, unsigned short* __restrict__ xbf, int X4,
                                const float* __restrict__ W1, const float* __restrict__ as1, const float* __restrict__ ad1,
                                const float* __restrict__ W2, const float* __restrict__ as2, const float* __restrict__ ad2,
                                const float* __restrict__ W3, const float* __restrict__ as3, const float* __restrict__ ad3,
                                unsigned short* __restrict__ Wa1, unsigned short* __restrict__ Wa2,
                                unsigned short* __restrict__ Wa3, unsigned short* __restrict__ Wc1,
                                unsigned short* __restrict__ Wc2, unsigned short* __restrict__ Wc3){
    if(blockIdx.x == 0 && threadIdx.x < 64){
        const unsigned long long v = e[threadIdx.x];
        const unsigned long long mask = __ballot(v >= (1ULL << 32));
        if(threadIdx.x == 0) *flag = (mask == 0ULL) ? 1 : 0;
    }
    int id = blockIdx.x * blockDim.x + threadIdx.x;
    if(id < N) deg[id] = 0;
    if(id < X4){
        const float4 v = *(const float4*)&x[(size_t)id * 4];
        ushort4v o;
        o[0] = f2bf(v.x); o[1] = f2bf(v.y); o[2] = f2bf(v.z); o[3] = f2bf(v.w);
        *(ushort4v*)&xbf[(size_t)id * 4] = o;
        return;
    }
    id -= X4;
    if(id < 16 * 128){ emit_wa(W1, as1, ad1, Wa1, 128, 64, id); return; }
    id -= 16 * 128;
    if(id < 16 * 64){ emit_wa(W2, as2, ad2, Wa2, 64, 64, id); return; }
    id -= 16 * 64;
    if(id < 16 * 64){ emit_wa(W3, as3, ad3, Wa3, 64, 40, id); return; }
    id -= 16 * 64;
    if(id < 64 * 512){ emit_wc(W1, Wc1, 128, 64, id); return; }
    id -= 64 * 512;
    if(id < 64 * 256){ emit_wc(W2, Wc2, 64, 64, id); return; }
    id -= 64 * 256;
    if(id < 48 * 256){ emit_wc(W3, Wc3, 64, 40, id); }
}

// ---------------- histogram off the raw edge buffer ----------------
__global__ void hist_kernel(const void* __restrict__ e, const int* __restrict__ flag,
                            int* __restrict__ deg, int E){
    const int i = blockIdx.x * blockDim.x + threadIdx.x;
    if(i < E){
        const int d = (*flag) ? (int)((const long long*)e)[E + i] : ((const int*)e)[E + i];
        atomicAdd(&deg[d], 1);
    }
}

// ---------------- CSR build (hierarchical scan) ----------------
__global__ __launch_bounds__(512) void scan1_kernel(const int* __restrict__ deg,
                                                    int* __restrict__ excl,
                                                    int* __restrict__ bsum, int n){
    __shared__ int sh[512];
    const int t = threadIdx.x;
    const int gid = blockIdx.x * 512 + t;
    const int v = (gid < n) ? deg[gid] : 0;
    sh[t] = v;
    __syncthreads();
    for(int off = 1; off < 512; off <<= 1){
        const int add = (t >= off) ? sh[t - off] : 0;
        __syncthreads();
        sh[t] += add;
        __syncthreads();
    }
    if(gid < n) excl[gid] = sh[t] - v;
    if(t == 511) bsum[blockIdx.x] = sh[511];
}

__global__ __launch_bounds__(128) void scan2_kernel(int* __restrict__ bsum, int nb){
    __shared__ int sh[128];
    const int t = threadIdx.x;
    const int v = (t < nb) ? bsum[t] : 0;
    sh[t] = v;
    __syncthreads();
    for(int off = 1; off < 128; off <<= 1){
        const int add = (t >= off) ? sh[t - off] : 0;
        __syncthreads();
        sh[t] += add;
        __syncthreads();
    }
    if(t < nb) bsum[t] = sh[t] - v;
}

__global__ void scan3_kernel(const int* __restrict__ excl, const int* __restrict__ bsum,
                             int* __restrict__ row_ptr, int* __restrict__ cursor,
                             int n, int E){
    const int gid = blockIdx.x * blockDim.x + threadIdx.x;
    if(gid < n){
        const int r = excl[gid] + bsum[gid >> 9];
        row_ptr[gid] = r;
        cursor[gid] = r;
    }
    if(gid == 0) row_ptr[n] = E;
}

__global__ void scatter_kernel(const void* __restrict__ e, const int* __restrict__ flag,
                               int* __restrict__ cursor, int* __restrict__ col, int E){
    const int i = blockIdx.x * blockDim.x + threadIdx.x;
    if(i < E){
        int s, d;
        if(*flag){ s = (int)((const long long*)e)[i]; d = (int)((const long long*)e)[E + i]; }
        else     { s = ((const int*)e)[i];            d = ((const int*)e)[E + i]; }
        const int pos = atomicAdd(&cursor[d], 1);
        col[pos] = s;
    }
}

// ---------------- alpha GEMM (layer 1 only): ea/ed = exp(A @ Wa) ----------------
template<int K>
__global__ __launch_bounds__(256) void agemm_kernel(const unsigned short* __restrict__ A,
                                                    const unsigned short* __restrict__ Wa,
                                                    float* __restrict__ ea, float* __restrict__ ed,
                                                    int M){
    const int lane = threadIdx.x & 63;
    const int wave = threadIdx.x >> 6;
    const int quad = lane >> 4;
    const int l16 = lane & 15;
    const int bm = blockIdx.x * 64;
    const int m = min(bm + wave * 16 + l16, M - 1);
    f32x4 acc = {0,0,0,0};
    #pragma unroll
    for(int k0 = 0; k0 < K; k0 += 32){
        const short8v a = *(const short8v*)&A[(size_t)m * K + k0 + quad * 8];
        const short8v b = *(const short8v*)&Wa[(size_t)l16 * K + k0 + quad * 8];
        acc = __builtin_amdgcn_mfma_f32_16x16x32_bf16(a, b, acc, 0, 0, 0);
    }
    if(l16 < 8){
        const int h = l16 & 3;
        float* dst = (l16 < 4) ? ea : ed;
        const int rbase = bm + wave * 16 + quad * 4;
        #pragma unroll
        for(int r = 0; r < 4; r++){
            const int row = rbase + r;
            if(row < M){
                const float v = acc[r];
                *(f32x2*)&dst[(size_t)row * 8 + 2 * h] = (f32x2){__expf(v), __expf(NEG_SLOPE * v)};
            }
        }
    }
}

// ---------------- fused gather + post-GEMM (+alpha / +log_softmax) ----------------
// Block = 16 nodes, 16 waves (1024 threads). Phase 1: wave w aggregates node
// nb+w into LDS row lg[w] -- identical per-wave shape to the proven standalone
// gather (1 node/wave, max TLP). Phase 2: 16x NC GEMM with 4-way K-split:
// wave = (tile t, chunk q); q>0 partials staged in padded LDS, q==0 reduces and
// runs the epilogue. ALPHA: h rows round-trip LDS; wave 0 runs the 2 Wa MFMAs
// and emits next layer's pre-exponentiated ea/ed (ping-pong buffers -- no race).
// FINAL: f32 LDS tile + 16-lane shuffle-reduce log_softmax on threads 0..255.
template<int K, int NC, bool FINAL, bool ALPHA>
__global__ __launch_bounds__(1024) void fused_kernel(const unsigned short* __restrict__ X,
                                                     const int* __restrict__ row_ptr,
                                                     const int* __restrict__ col,
                                                     const float* __restrict__ ea,
                                                     const float* __restrict__ ed,
                                                     const unsigned short* __restrict__ Bt,
                                                     const float* __restrict__ bias,
                                                     void* __restrict__ outv,
                                                     const unsigned short* __restrict__ Wa,
                                                     float* __restrict__ ea_o,
                                                     float* __restrict__ ed_o){
    constexpr int KC = 4 * K;          // g-row length: 512 (K=128) or 256 (K=64)
    constexpr int CPL = K / 16;        // channels per lane: 8 or 4
    constexpr int PAIRS = CPL / 2;
    constexpr int LSTR = KC + 8;       // +16B pad: rows stay 16B-aligned, banks spread
    constexpr int NT = (NC + 15) / 16; // 4 (NC=64) or 3 (NC=40)
    constexpr int KCH = KC / 4;        // K per chunk: 128 or 64
    __shared__ unsigned short lg[16][LSTR];
    __shared__ float pt[3][NT][16][20];          // q=1..3 partials, +4 pad (2-way banks)
    __shared__ unsigned short lh[ALPHA ? 16 : 1][72];
    __shared__ float lo[FINAL ? 16 : 1][48];

    const int lane = threadIdx.x & 63;
    const int wave = threadIdx.x >> 6;           // 0..15
    const int slot = lane >> 4;                  // edge slot (gather) / k-quad (GEMM)
    const int pos  = lane & 15;                  // channel lane (gather) / row|col (GEMM)
    const int nb   = blockIdx.x * 16;            // 3125 * 16 == 50000: no row guards

    // ---- phase 1: one node per wave (verbatim proven gather shape) ----
    {
        const int n = nb + wave;
        const int rs = row_ptr[n], re = row_ptr[n + 1];
        const int T = re - rs + 1;               // edges + virtual self loop
        const float4 edA = *(const float4*)&ed[(size_t)n * 8];
        const float4 edB = *(const float4*)&ed[(size_t)n * 8 + 4];

        f32x2 acc[4][PAIRS];
        #pragma unroll
        for(int h = 0; h < 4; h++)
            #pragma unroll
            for(int p = 0; p < PAIRS; p++) acc[h][p] = (f32x2){0.f, 0.f};
        float dnm[4] = {0.f, 0.f, 0.f, 0.f};

        auto body = [&](int e){
            const int s = (e < re) ? col[e] : n; // e==re => self loop
            const float4 eaA = *(const float4*)&ea[(size_t)s * 8];
            const float4 eaB = *(const float4*)&ea[(size_t)s * 8 + 4];
            const float w0 = fmaxf(eaA.x * edA.x, eaA.y * edA.y);
            const float w1 = fmaxf(eaA.z * edA.z, eaA.w * edA.w);
            const float w2 = fmaxf(eaB.x * edB.x, eaB.y * edB.y);
            const float w3 = fmaxf(eaB.z * edB.z, eaB.w * edB.w);
            dnm[0] += w0; dnm[1] += w1; dnm[2] += w2; dnm[3] += w3;
            unsigned u[PAIRS];
            if constexpr(PAIRS == 2){
                const uint2 t2 = *(const uint2*)&X[(size_t)s * K + pos * CPL];
                u[0] = t2.x; u[1] = t2.y;
            } else {
                const uint4 t4 = *(const uint4*)&X[(size_t)s * K + pos * CPL];
                u[0] = t4.x; u[1] = t4.y; u[2] = t4.z; u[3] = t4.w;
            }
            #pragma unroll
            for(int p = 0; p < PAIRS; p++){
                const f32x2 v = {__uint_as_float(u[p] << 16), __uint_as_float(u[p] & 0xffff0000u)};
                acc[0][p] += (f32x2){w0, w0} * v;
                acc[1][p] += (f32x2){w1, w1} * v;
                acc[2][p] += (f32x2){w2, w2} * v;
                acc[3][p] += (f32x2){w3, w3} * v;
            }
        };

        int k = 0;
        for(; k + 8 <= T; k += 8){ body(rs + k + slot); body(rs + k + 4 + slot); }
        for(; k + 4 <= T; k += 4){ body(rs + k + slot); }
        if(k < T && slot < T - k){ body(rs + k + slot); }

        #pragma unroll
        for(int msk = 16; msk < 64; msk <<= 1){
            #pragma unroll
            for(int h = 0; h < 4; h++){
                #pragma unroll
                for(int p = 0; p < PAIRS; p++){
                    acc[h][p][0] += __shfl_xor(acc[h][p][0], msk);
                    acc[h][p][1] += __shfl_xor(acc[h][p][1], msk);
                }
                dnm[h] += __shfl_xor(dnm[h], msk);
            }
        }
        if(lane < 16){
            #pragma unroll
            for(int h = 0; h < 4; h++){
                const float sc = 1.f / dnm[h];
                if constexpr(PAIRS == 2){
                    ushort4v o;
                    o[0] = f2bf(acc[h][0][0] * sc); o[1] = f2bf(acc[h][0][1] * sc);
                    o[2] = f2bf(acc[h][1][0] * sc); o[3] = f2bf(acc[h][1][1] * sc);
                    *(ushort4v*)&lg[wave][h * K + pos * CPL] = o;
                } else {
                    ushort8v o;
                    #pragma unroll
                    for(int p = 0; p < 4; p++){
                        o[2*p]   = f2bf(acc[h][p][0] * sc);
                        o[2*p+1] = f2bf(acc[h][p][1] * sc);
                    }
                    *(ushort8v*)&lg[wave][h * K + pos * CPL] = o;
                }
            }
        }
    }
    __syncthreads();

    // ---- phase 2: 16xNC GEMM, 4-way K-split across waves ----
    const int t = wave & 3;                      // column tile
    const int q = wave >> 2;                     // K chunk
    f32x4 acc4 = {0, 0, 0, 0};
    if(t < NT){
        const int c = t * 16 + pos;
        const int kbeg = q * KCH;
        #pragma unroll
        for(int k0 = kbeg; k0 < kbeg + KCH; k0 += 32){
            const short8v a = *(const short8v*)&lg[pos][k0 + slot * 8];
            const short8v b = *(const short8v*)&Bt[(size_t)c * KC + k0 + slot * 8];
            acc4 = __builtin_amdgcn_mfma_f32_16x16x32_bf16(a, b, acc4, 0, 0, 0);
        }
        if(q > 0){
            #pragma unroll
            for(int r = 0; r < 4; r++) pt[q - 1][t][slot * 4 + r][pos] = acc4[r];
        }
    }
    __syncthreads();

    if constexpr(!FINAL){
        if(q == 0){                              // waves 0..3: reduce + epilogue
            #pragma unroll
            for(int r = 0; r < 4; r++)
                acc4[r] += pt[0][t][slot * 4 + r][pos] + pt[1][t][slot * 4 + r][pos]
                         + pt[2][t][slot * 4 + r][pos];
            unsigned short* out = (unsigned short*)outv;
            const int c = t * 16 + pos;
            const float bc = bias[c];
            #pragma unroll
            for(int r = 0; r < 4; r++){
                const unsigned short hb = f2bf(fmaxf(acc4[r] + bc, 0.f));
                out[(size_t)(nb + slot * 4 + r) * NC + c] = hb;
                if constexpr(ALPHA) lh[slot * 4 + r][c] = hb;
            }
        }
        if constexpr(ALPHA){
            __syncthreads();
            if(wave == 0){
                f32x4 a4 = {0, 0, 0, 0};
                #pragma unroll
                for(int k0 = 0; k0 < 64; k0 += 32){
                    const short8v a = *(const short8v*)&lh[pos][k0 + slot * 8];
                    const short8v b = *(const short8v*)&Wa[(size_t)pos * 64 + k0 + slot * 8];
                    a4 = __builtin_amdgcn_mfma_f32_16x16x32_bf16(a, b, a4, 0, 0, 0);
                }
                if(pos < 8){
                    const int h = pos & 3;
                    float* dst = (pos < 4) ? ea_o : ed_o;
                    #pragma unroll
                    for(int r = 0; r < 4; r++){
                        const int row = nb + slot * 4 + r;
                        const float v = a4[r];
                        *(f32x2*)&dst[(size_t)row * 8 + 2 * h] = (f32x2){__expf(v), __expf(NEG_SLOPE * v)};
                    }
                }
            }
        }
    } else {
        if(q == 0 && t < NT){                    // waves 0..2: reduce into lo
            #pragma unroll
            for(int r = 0; r < 4; r++){
                const float v = acc4[r] + pt[0][t][slot * 4 + r][pos]
                              + pt[1][t][slot * 4 + r][pos] + pt[2][t][slot * 4 + r][pos];
                const int c = t * 16 + pos;
                const bool valid = c < 40;
                lo[slot * 4 + r][c] = valid ? fmaxf(v + bias[c], 0.f) : -INFINITY;
            }
        }
        __syncthreads();
        if(threadIdx.x < 256){
            // row-wise log_softmax: 16 threads per row (16-aligned lane groups)
            const int r  = threadIdx.x >> 4;
            const int cc = threadIdx.x & 15;
            const float o0 = lo[r][cc];
            const float o1 = lo[r][cc + 16];
            const float o2 = lo[r][cc + 32];
            float mx = fmaxf(fmaxf(o0, o1), o2);
            #pragma unroll
            for(int off = 1; off < 16; off <<= 1) mx = fmaxf(mx, __shfl_xor(mx, off));
            float se = __expf(o0 - mx) + __expf(o1 - mx) + ((o2 > -INFINITY) ? __expf(o2 - mx) : 0.f);
            #pragma unroll
            for(int off = 1; off < 16; off <<= 1) se += __shfl_xor(se, off);
            const float lz = mx + logf(se);
            float* out = (float*)outv;
            const size_t rb = (size_t)(nb + r) * 40;
            out[rb + cc] = o0 - lz;
            out[rb + cc + 16] = o1 - lz;
            if(cc < 8) out[rb + cc + 32] = o2 - lz;
        }
    }
}

// ---------------- driver ----------------
extern "C" void kernel_launch(void* const* d_in, const int* in_sizes, int n_in,
                              void* d_out, int out_size, void* d_ws, size_t ws_size,
                              hipStream_t stream){
    const int N = NNODES;
    const int E = in_sizes[1] / 2;

    const float* x   = (const float*)d_in[0];
    const float* W1  = (const float*)d_in[2];
    const float* as1 = (const float*)d_in[3];
    const float* ad1 = (const float*)d_in[4];
    const float* b1  = (const float*)d_in[5];
    const float* W2  = (const float*)d_in[6];
    const float* as2 = (const float*)d_in[7];
    const float* ad2 = (const float*)d_in[8];
    const float* b2  = (const float*)d_in[9];
    const float* W3  = (const float*)d_in[10];
    const float* as3 = (const float*)d_in[11];
    const float* ad3 = (const float*)d_in[12];
    const float* b3  = (const float*)d_in[13];

    char* ws = (char*)d_ws;
    size_t off = 0;
    auto alloc = [&](size_t bytes) -> void* {
        void* p = ws + off;
        off = (off + bytes + 255) & ~(size_t)255;
        return p;
    };
    int*   flag    = (int*)  alloc(4);
    int*   row_ptr = (int*)  alloc((size_t)(N + 1) * 4);
    int*   colv    = (int*)  alloc((size_t)E * 4);
    int*   cursor  = (int*)  alloc((size_t)N * 4);
    int*   deg     = (int*)  alloc((size_t)N * 4);
    int*   excl    = (int*)  alloc((size_t)N * 4);
    int*   bsum    = (int*)  alloc(128 * 4);
    unsigned short* xbf = (unsigned short*)alloc((size_t)N * 128 * 2);
    unsigned short* Wa1 = (unsigned short*)alloc(16 * 128 * 2);
    unsigned short* Wa2 = (unsigned short*)alloc(16 * 64 * 2);
    unsigned short* Wa3 = (unsigned short*)alloc(16 * 64 * 2);
    unsigned short* Wc1 = (unsigned short*)alloc((size_t)64 * 512 * 2);
    unsigned short* Wc2 = (unsigned short*)alloc((size_t)64 * 256 * 2);
    unsigned short* Wc3 = (unsigned short*)alloc((size_t)48 * 256 * 2);
    float* eav0 = (float*)alloc((size_t)N * 8 * 4);
    float* edv0 = (float*)alloc((size_t)N * 8 * 4);
    float* eav1 = (float*)alloc((size_t)N * 8 * 4);
    float* edv1 = (float*)alloc((size_t)N * 8 * 4);
    unsigned short* h1  = (unsigned short*)alloc((size_t)N * 64 * 2);
    unsigned short* h2  = (unsigned short*)alloc((size_t)N * 64 * 2);
    (void)ws_size;

    const void* eraw = d_in[1];

    const int X4 = N * 128 / 4;
    const int prepTotal = X4 + 16*128 + 16*64 + 16*64 + 64*512 + 64*256 + 48*256;
    initprep_kernel<<<(prepTotal + 255) / 256, 256, 0, stream>>>(
        (const unsigned long long*)eraw, flag, deg, N, x, xbf, X4,
        W1, as1, ad1, W2, as2, ad2, W3, as3, ad3,
        Wa1, Wa2, Wa3, Wc1, Wc2, Wc3);

    hist_kernel<<<(E + 255) / 256, 256, 0, stream>>>(eraw, flag, deg, E);
    const int nbScan = (N + 511) / 512;
    scan1_kernel<<<nbScan, 512, 0, stream>>>(deg, excl, bsum, N);
    scan2_kernel<<<1, 128, 0, stream>>>(bsum, nbScan);
    scan3_kernel<<<(N + 255) / 256, 256, 0, stream>>>(excl, bsum, row_ptr, cursor, N, E);
    scatter_kernel<<<(E + 255) / 256, 256, 0, stream>>>(eraw, flag, cursor, colv, E);

    const int mBlocks = (N + 63) / 64;         // 782
    const int fBlocks = N / 16;                // 3125 (exact)

    // layer 1 alpha from raw features
    agemm_kernel<128><<<mBlocks, 256, 0, stream>>>(xbf, Wa1, eav0, edv0, N);

    // layer 1: gather+GEMM fused; emits h1 and layer-2 alpha (ping-pong ea/ed)
    fused_kernel<128, 64, false, true><<<fBlocks, 1024, 0, stream>>>(
        xbf, row_ptr, colv, eav0, edv0, Wc1, b1, h1, Wa2, eav1, edv1);

    // layer 2: emits h2 and layer-3 alpha
    fused_kernel<64, 64, false, true><<<fBlocks, 1024, 0, stream>>>(
        h1, row_ptr, colv, eav1, edv1, Wc2, b2, h2, Wa3, eav0, edv0);

    // layer 3: fused log_softmax to output
    fused_kernel<64, 40, true, false><<<fBlocks, 1024, 0, stream>>>(
        h2, row_ptr, colv, eav0, edv0, Wc3, b3, d_out, nullptr, nullptr, nullptr);
}

// Round 3
// 475.670 us; speedup vs baseline: 1.0208x; 1.0208x over previous
//
#include <hip/hip_runtime.h>
#include <math.h>

#define NNODES 50000
#define NEG_SLOPE 0.2f

typedef unsigned short ushort8v __attribute__((ext_vector_type(8)));
typedef unsigned short ushort4v __attribute__((ext_vector_type(4)));
typedef short short8v __attribute__((ext_vector_type(8)));
typedef float f32x4 __attribute__((ext_vector_type(4)));
typedef float f32x2 __attribute__((ext_vector_type(2)));

__device__ __forceinline__ unsigned short f2bf(float f){
    unsigned u = __float_as_uint(f);
    u += 0x7fff + ((u >> 16) & 1);   // RNE; inputs finite
    return (unsigned short)(u >> 16);
}

// ---------------- prep: combined projection weight, transposed, + appended Wa rows ----
// WpT layout [272][Kin]: rows 0..255 = W^T as [h*64+c][k] (c>=C zero-padded);
// rows 256..271 = Wa rows (j<8: dot(W[:,h,:], a[h,:]), j>=8 zero) -- the alpha GEMM.
__device__ __forceinline__ void emit_wpt(const float* __restrict__ W, const float* __restrict__ a_s,
                                         const float* __restrict__ a_d, unsigned short* __restrict__ Wt,
                                         int Kin, int C, int id){
    const int j = id / Kin, k = id - j * Kin;
    float v = 0.f;
    if(j < 256){
        const int h = j >> 6, c = j & 63;
        v = (c < C) ? W[(size_t)k * (4 * C) + h * C + c] : 0.f;
    } else {
        const int n = j - 256;
        if(n < 8){
            const int hh = n & 3;
            const float* av = (n < 4) ? a_s : a_d;
            for(int c = 0; c < C; c++) v += W[(size_t)k * (4 * C) + hh * C + c] * av[hh * C + c];
        }
    }
    Wt[id] = f2bf(v);
}

// ---------------- init+prep: detect (block 0) + zero deg + xbf + WpT* ----------------
__global__ void initprep_kernel(const unsigned long long* __restrict__ e, int* __restrict__ flag,
                                int* __restrict__ deg, int N,
                                const float* __restrict__ x, unsigned short* __restrict__ xbf, int X4,
                                const float* __restrict__ W1, const float* __restrict__ as1, const float* __restrict__ ad1,
                                const float* __restrict__ W2, const float* __restrict__ as2, const float* __restrict__ ad2,
                                const float* __restrict__ W3, const float* __restrict__ as3, const float* __restrict__ ad3,
                                unsigned short* __restrict__ WpT1, unsigned short* __restrict__ WpT2,
                                unsigned short* __restrict__ WpT3){
    if(blockIdx.x == 0 && threadIdx.x < 64){
        const unsigned long long v = e[threadIdx.x];
        const unsigned long long mask = __ballot(v >= (1ULL << 32));
        if(threadIdx.x == 0) *flag = (mask == 0ULL) ? 1 : 0;
    }
    int id = blockIdx.x * blockDim.x + threadIdx.x;
    if(id < N) deg[id] = 0;
    if(id < X4){
        const float4 v = *(const float4*)&x[(size_t)id * 4];
        ushort4v o;
        o[0] = f2bf(v.x); o[1] = f2bf(v.y); o[2] = f2bf(v.z); o[3] = f2bf(v.w);
        *(ushort4v*)&xbf[(size_t)id * 4] = o;
        return;
    }
    id -= X4;
    if(id < 272 * 128){ emit_wpt(W1, as1, ad1, WpT1, 128, 64, id); return; }
    id -= 272 * 128;
    if(id < 272 * 64){ emit_wpt(W2, as2, ad2, WpT2, 64, 64, id); return; }
    id -= 272 * 64;
    if(id < 272 * 64){ emit_wpt(W3, as3, ad3, WpT3, 64, 40, id); }
}

// ---------------- histogram off the raw edge buffer ----------------
__global__ void hist_kernel(const void* __restrict__ e, const int* __restrict__ flag,
                            int* __restrict__ deg, int E){
    const int i = blockIdx.x * blockDim.x + threadIdx.x;
    if(i < E){
        const int d = (*flag) ? (int)((const long long*)e)[E + i] : ((const int*)e)[E + i];
        atomicAdd(&deg[d], 1);
    }
}

// ---------------- CSR build (hierarchical scan) ----------------
__global__ __launch_bounds__(512) void scan1_kernel(const int* __restrict__ deg,
                                                    int* __restrict__ excl,
                                                    int* __restrict__ bsum, int n){
    __shared__ int sh[512];
    const int t = threadIdx.x;
    const int gid = blockIdx.x * 512 + t;
    const int v = (gid < n) ? deg[gid] : 0;
    sh[t] = v;
    __syncthreads();
    for(int off = 1; off < 512; off <<= 1){
        const int add = (t >= off) ? sh[t - off] : 0;
        __syncthreads();
        sh[t] += add;
        __syncthreads();
    }
    if(gid < n) excl[gid] = sh[t] - v;
    if(t == 511) bsum[blockIdx.x] = sh[511];
}

__global__ __launch_bounds__(128) void scan2_kernel(int* __restrict__ bsum, int nb){
    __shared__ int sh[128];
    const int t = threadIdx.x;
    const int v = (t < nb) ? bsum[t] : 0;
    sh[t] = v;
    __syncthreads();
    for(int off = 1; off < 128; off <<= 1){
        const int add = (t >= off) ? sh[t - off] : 0;
        __syncthreads();
        sh[t] += add;
        __syncthreads();
    }
    if(t < nb) bsum[t] = sh[t] - v;
}

__global__ void scan3_kernel(const int* __restrict__ excl, const int* __restrict__ bsum,
                             int* __restrict__ row_ptr, int* __restrict__ cursor,
                             int n, int E){
    const int gid = blockIdx.x * blockDim.x + threadIdx.x;
    if(gid < n){
        const int r = excl[gid] + bsum[gid >> 9];
        row_ptr[gid] = r;
        cursor[gid] = r;
    }
    if(gid == 0) row_ptr[n] = E;
}

__global__ void scatter_kernel(const void* __restrict__ e, const int* __restrict__ flag,
                               int* __restrict__ cursor, int* __restrict__ col, int E){
    const int i = blockIdx.x * blockDim.x + threadIdx.x;
    if(i < E){
        int s, d;
        if(*flag){ s = (int)((const long long*)e)[i]; d = (int)((const long long*)e)[E + i]; }
        else     { s = ((const int*)e)[i];            d = ((const int*)e)[E + i]; }
        const int pos = atomicAdd(&cursor[d], 1);
        col[pos] = s;
    }
}

// ---------------- projection GEMM: xp = A @ WpT^T (cols 0..255) + alpha (cols 256..271)
// Block 256 = 4 waves x 16 rows. Per wave: A-row frags held in regs, loop 17 col-tiles.
// Tile 16 emits the pre-exponentiated ea/ed for the NEXT gather (replaces agemm).
template<int K>
__global__ __launch_bounds__(256) void xpgemm_kernel(const unsigned short* __restrict__ A,
                                                     const unsigned short* __restrict__ Bt,
                                                     unsigned short* __restrict__ xp,
                                                     float* __restrict__ ea, float* __restrict__ ed,
                                                     int M){
    constexpr int KK = K / 32;
    const int lane = threadIdx.x & 63;
    const int wave = threadIdx.x >> 6;
    const int quad = lane >> 4;
    const int l16 = lane & 15;
    const int bm = blockIdx.x * 64;
    const int m = min(bm + wave * 16 + l16, M - 1);
    const int rbase = bm + wave * 16 + quad * 4;

    short8v af[KK];
    #pragma unroll
    for(int kk = 0; kk < KK; kk++)
        af[kk] = *(const short8v*)&A[(size_t)m * K + kk * 32 + quad * 8];

    #pragma unroll
    for(int t = 0; t < 17; t++){
        f32x4 acc = {0, 0, 0, 0};
        #pragma unroll
        for(int kk = 0; kk < KK; kk++){
            const short8v b = *(const short8v*)&Bt[(size_t)(t * 16 + l16) * K + kk * 32 + quad * 8];
            acc = __builtin_amdgcn_mfma_f32_16x16x32_bf16(af[kk], b, acc, 0, 0, 0);
        }
        if(t < 16){
            const int c = t * 16 + l16;
            #pragma unroll
            for(int r = 0; r < 4; r++){
                const int row = rbase + r;
                if(row < M) xp[(size_t)row * 256 + c] = f2bf(acc[r]);
            }
        } else if(l16 < 8){
            const int h = l16 & 3;
            float* dst = (l16 < 4) ? ea : ed;
            #pragma unroll
            for(int r = 0; r < 4; r++){
                const int row = rbase + r;
                if(row < M){
                    const float v = acc[r];
                    *(f32x2*)&dst[(size_t)row * 8 + 2 * h] = (f32x2){__expf(v), __expf(NEG_SLOPE * v)};
                }
            }
        }
    }
}

// ---------------- projected gather: out = relu(0.25 * sum_h (sum_e w*xp[s,h,:])/dnm_h + b)
// Block 256 = 4 waves, 1 node/wave (proven scheduling shape, no barrier).
// Phase A: lane e owns edge e -- coalesced col load, independent ea loads, w[4] + s
//          stashed in wave-private LDS (within-wave lgkmcnt ordering, no barrier).
// Phase B: loop edges; all 64 lanes load the 512B xp row cooperatively (8B/lane),
//          4-way unrolled for MLP; lane owns 4 channels of one head (h=lane>>4).
// Epilogue: per-head normalize, head-mean via 2 shfl_xor, +bias, relu -> bf16 h
//           (or fused log_softmax -> f32 out for FINAL).
template<bool FINAL>
__global__ __launch_bounds__(256) void gatherp_kernel(const unsigned short* __restrict__ xp,
                                                      const int* __restrict__ row_ptr,
                                                      const int* __restrict__ col,
                                                      const float* __restrict__ ea,
                                                      const float* __restrict__ ed,
                                                      const float* __restrict__ bias,
                                                      void* __restrict__ outv){
    __shared__ int   ls[4][64];
    __shared__ float lw[4][64][4];
    const int lane = threadIdx.x & 63;
    const int wave = threadIdx.x >> 6;
    const int h    = lane >> 4;
    const int pos  = lane & 15;
    const int n    = blockIdx.x * 4 + wave;
    const int rs = row_ptr[n], re = row_ptr[n + 1];
    const int T = re - rs + 1;                    // edges + virtual self loop
    const float4 edA = *(const float4*)&ed[(size_t)n * 8];
    const float4 edB = *(const float4*)&ed[(size_t)n * 8 + 4];

    float a0 = 0.f, a1 = 0.f, a2 = 0.f, a3 = 0.f;
    float d0 = 0.f, d1 = 0.f, d2 = 0.f, d3 = 0.f;

    for(int base = 0; base < T; base += 64){
        const int ecnt = min(T - base, 64);
        if(lane < ecnt){
            const int e = rs + base + lane;
            const int s = (e < re) ? col[e] : n;  // e==re => self loop
            const float4 eaA = *(const float4*)&ea[(size_t)s * 8];
            const float4 eaB = *(const float4*)&ea[(size_t)s * 8 + 4];
            const float w0 = fmaxf(eaA.x * edA.x, eaA.y * edA.y);
            const float w1 = fmaxf(eaA.z * edA.z, eaA.w * edA.w);
            const float w2 = fmaxf(eaB.x * edB.x, eaB.y * edB.y);
            const float w3 = fmaxf(eaB.z * edB.z, eaB.w * edB.w);
            d0 += w0; d1 += w1; d2 += w2; d3 += w3;
            ls[wave][lane] = s;
            *(f32x4*)&lw[wave][lane][0] = (f32x4){w0, w1, w2, w3};
        }
        auto body = [&](int e){
            const int s   = ls[wave][e];          // broadcast
            const float w = lw[wave][e][h];       // 4 banks, conflict-free
            const uint2 u = *(const uint2*)&xp[(size_t)s * 256 + lane * 4];
            a0 += w * __uint_as_float(u.x << 16);
            a1 += w * __uint_as_float(u.x & 0xffff0000u);
            a2 += w * __uint_as_float(u.y << 16);
            a3 += w * __uint_as_float(u.y & 0xffff0000u);
        };
        int e = 0;
        for(; e + 4 <= ecnt; e += 4){ body(e); body(e + 1); body(e + 2); body(e + 3); }
        for(; e < ecnt; e++) body(e);
    }

    // denominators: reduce per-lane partials over all 64 lanes
    #pragma unroll
    for(int msk = 1; msk < 64; msk <<= 1){
        d0 += __shfl_xor(d0, msk); d1 += __shfl_xor(d1, msk);
        d2 += __shfl_xor(d2, msk); d3 += __shfl_xor(d3, msk);
    }
    const float dn = (h == 0) ? d0 : (h == 1) ? d1 : (h == 2) ? d2 : d3;
    const float sc = 0.25f / dn;
    a0 *= sc; a1 *= sc; a2 *= sc; a3 *= sc;
    // head-mean: sum the 4 head groups (stride-16 lanes)
    #pragma unroll
    for(int msk = 16; msk < 64; msk <<= 1){
        a0 += __shfl_xor(a0, msk); a1 += __shfl_xor(a1, msk);
        a2 += __shfl_xor(a2, msk); a3 += __shfl_xor(a3, msk);
    }
    const int c0 = pos * 4;

    if constexpr(!FINAL){
        if(h == 0){
            const float4 b4 = *(const float4*)&bias[c0];
            unsigned short* out = (unsigned short*)outv;
            ushort4v o;
            o[0] = f2bf(fmaxf(a0 + b4.x, 0.f));
            o[1] = f2bf(fmaxf(a1 + b4.y, 0.f));
            o[2] = f2bf(fmaxf(a2 + b4.z, 0.f));
            o[3] = f2bf(fmaxf(a3 + b4.w, 0.f));
            *(ushort4v*)&out[(size_t)n * 64 + c0] = o;
        }
    } else {
        // 40 valid channels; lanes replicated across head groups -> all compute
        float4 b4 = {0.f, 0.f, 0.f, 0.f};
        if(c0 < 40) b4 = *(const float4*)&bias[c0];
        const float o0 = (c0     < 40) ? fmaxf(a0 + b4.x, 0.f) : -INFINITY;
        const float o1 = (c0 + 1 < 40) ? fmaxf(a1 + b4.y, 0.f) : -INFINITY;
        const float o2 = (c0 + 2 < 40) ? fmaxf(a2 + b4.z, 0.f) : -INFINITY;
        const float o3 = (c0 + 3 < 40) ? fmaxf(a3 + b4.w, 0.f) : -INFINITY;
        float mx = fmaxf(fmaxf(o0, o1), fmaxf(o2, o3));
        #pragma unroll
        for(int msk = 1; msk < 16; msk <<= 1) mx = fmaxf(mx, __shfl_xor(mx, msk));
        float se = ((o0 > -INFINITY) ? __expf(o0 - mx) : 0.f)
                 + ((o1 > -INFINITY) ? __expf(o1 - mx) : 0.f)
                 + ((o2 > -INFINITY) ? __expf(o2 - mx) : 0.f)
                 + ((o3 > -INFINITY) ? __expf(o3 - mx) : 0.f);
        #pragma unroll
        for(int msk = 1; msk < 16; msk <<= 1) se += __shfl_xor(se, msk);
        const float lz = mx + logf(se);
        if(h == 0 && c0 < 40){
            float* out = (float*)outv;
            *(f32x4*)&out[(size_t)n * 40 + c0] = (f32x4){o0 - lz, o1 - lz, o2 - lz, o3 - lz};
        }
    }
}

// ---------------- driver ----------------
extern "C" void kernel_launch(void* const* d_in, const int* in_sizes, int n_in,
                              void* d_out, int out_size, void* d_ws, size_t ws_size,
                              hipStream_t stream){
    const int N = NNODES;
    const int E = in_sizes[1] / 2;

    const float* x   = (const float*)d_in[0];
    const float* W1  = (const float*)d_in[2];
    const float* as1 = (const float*)d_in[3];
    const float* ad1 = (const float*)d_in[4];
    const float* b1  = (const float*)d_in[5];
    const float* W2  = (const float*)d_in[6];
    const float* as2 = (const float*)d_in[7];
    const float* ad2 = (const float*)d_in[8];
    const float* b2  = (const float*)d_in[9];
    const float* W3  = (const float*)d_in[10];
    const float* as3 = (const float*)d_in[11];
    const float* ad3 = (const float*)d_in[12];
    const float* b3  = (const float*)d_in[13];

    char* ws = (char*)d_ws;
    size_t off = 0;
    auto alloc = [&](size_t bytes) -> void* {
        void* p = ws + off;
        off = (off + bytes + 255) & ~(size_t)255;
        return p;
    };
    int*   flag    = (int*)  alloc(4);
    int*   row_ptr = (int*)  alloc((size_t)(N + 1) * 4);
    int*   colv    = (int*)  alloc((size_t)E * 4);
    int*   cursor  = (int*)  alloc((size_t)N * 4);
    int*   deg     = (int*)  alloc((size_t)N * 4);
    int*   excl    = (int*)  alloc((size_t)N * 4);
    int*   bsum    = (int*)  alloc(128 * 4);
    unsigned short* xbf  = (unsigned short*)alloc((size_t)N * 128 * 2);
    unsigned short* WpT1 = (unsigned short*)alloc((size_t)272 * 128 * 2);
    unsigned short* WpT2 = (unsigned short*)alloc((size_t)272 * 64 * 2);
    unsigned short* WpT3 = (unsigned short*)alloc((size_t)272 * 64 * 2);
    float* eav = (float*)alloc((size_t)N * 8 * 4);
    float* edv = (float*)alloc((size_t)N * 8 * 4);
    unsigned short* xpv = (unsigned short*)alloc((size_t)N * 256 * 2);
    unsigned short* h1  = (unsigned short*)alloc((size_t)N * 64 * 2);
    unsigned short* h2  = (unsigned short*)alloc((size_t)N * 64 * 2);
    (void)ws_size;

    const void* eraw = d_in[1];

    const int X4 = N * 128 / 4;
    const int prepTotal = X4 + 272 * 128 + 272 * 64 + 272 * 64;
    initprep_kernel<<<(prepTotal + 255) / 256, 256, 0, stream>>>(
        (const unsigned long long*)eraw, flag, deg, N, x, xbf, X4,
        W1, as1, ad1, W2, as2, ad2, W3, as3, ad3,
        WpT1, WpT2, WpT3);

    hist_kernel<<<(E + 255) / 256, 256, 0, stream>>>(eraw, flag, deg, E);
    const int nbScan = (N + 511) / 512;
    scan1_kernel<<<nbScan, 512, 0, stream>>>(deg, excl, bsum, N);
    scan2_kernel<<<1, 128, 0, stream>>>(bsum, nbScan);
    scan3_kernel<<<(N + 255) / 256, 256, 0, stream>>>(excl, bsum, row_ptr, cursor, N, E);
    scatter_kernel<<<(E + 255) / 256, 256, 0, stream>>>(eraw, flag, cursor, colv, E);

    const int mBlocks = (N + 63) / 64;         // 782
    const int nodeBlocks = N / 4;              // 12500

    // layer 1: project + alpha, then gather in projected space -> h1
    xpgemm_kernel<128><<<mBlocks, 256, 0, stream>>>(xbf, WpT1, xpv, eav, edv, N);
    gatherp_kernel<false><<<nodeBlocks, 256, 0, stream>>>(xpv, row_ptr, colv, eav, edv, b1, h1);

    // layer 2
    xpgemm_kernel<64><<<mBlocks, 256, 0, stream>>>(h1, WpT2, xpv, eav, edv, N);
    gatherp_kernel<false><<<nodeBlocks, 256, 0, stream>>>(xpv, row_ptr, colv, eav, edv, b2, h2);

    // layer 3: + fused log_softmax
    xpgemm_kernel<64><<<mBlocks, 256, 0, stream>>>(h2, WpT3, xpv, eav, edv, N);
    gatherp_kernel<true><<<nodeBlocks, 256, 0, stream>>>(xpv, row_ptr, colv, eav, edv, b3, d_out);
}

// Round 4
// 420.131 us; speedup vs baseline: 1.1558x; 1.1322x over previous
//
#include <hip/hip_runtime.h>
#include <math.h>

#define NNODES 50000
#define NEG_SLOPE 0.2f

typedef unsigned short ushort8v __attribute__((ext_vector_type(8)));
typedef unsigned short ushort4v __attribute__((ext_vector_type(4)));
typedef short short8v __attribute__((ext_vector_type(8)));
typedef float f32x4 __attribute__((ext_vector_type(4)));
typedef float f32x2 __attribute__((ext_vector_type(2)));

__device__ __forceinline__ unsigned short f2bf(float f){
    unsigned u = __float_as_uint(f);
    u += 0x7fff + ((u >> 16) & 1);   // RNE; inputs finite
    return (unsigned short)(u >> 16);
}

// ---------------- prep helpers ----------------
__device__ __forceinline__ void emit_wa(const float* __restrict__ W, const float* __restrict__ a_s,
                                        const float* __restrict__ a_d, unsigned short* __restrict__ Wt,
                                        int Kin, int C, int id){
    const int n = id / Kin, k = id - n * Kin;
    float v = 0.f;
    if(n < 8){
        const int hh = n & 3;
        const float* av = (n < 4) ? a_s : a_d;
        for(int c = 0; c < C; c++) v += W[(size_t)k * (4 * C) + hh * C + c] * av[hh * C + c];
    }
    Wt[id] = f2bf(v);
}

__device__ __forceinline__ void emit_wc(const float* __restrict__ W, unsigned short* __restrict__ Wt,
                                        int Kin, int C, int id){
    const int c = id / (4 * Kin);
    const int hk = id - c * (4 * Kin);
    const int h = hk / Kin, k = hk - h * Kin;
    const float v = (c < C) ? W[(size_t)k * (4 * C) + h * C + c] * 0.25f : 0.f;
    Wt[id] = f2bf(v);
}

// ---------------- init+prep: detect (block 0) + zero deg + xbf + Wa* + Wc* ----------------
__global__ void initprep_kernel(const unsigned long long* __restrict__ e, int* __restrict__ flag,
                                int* __restrict__ deg, int N,
                                const float* __restrict__ x, unsigned short* __restrict__ xbf, int X4,
                                const float* __restrict__ W1, const float* __restrict__ as1, const float* __restrict__ ad1,
                                const float* __restrict__ W2, const float* __restrict__ as2, const float* __restrict__ ad2,
                                const float* __restrict__ W3, const float* __restrict__ as3, const float* __restrict__ ad3,
                                unsigned short* __restrict__ Wa1, unsigned short* __restrict__ Wa2,
                                unsigned short* __restrict__ Wa3, unsigned short* __restrict__ Wc1,
                                unsigned short* __restrict__ Wc2, unsigned short* __restrict__ Wc3){
    if(blockIdx.x == 0 && threadIdx.x < 64){
        const unsigned long long v = e[threadIdx.x];
        const unsigned long long mask = __ballot(v >= (1ULL << 32));
        if(threadIdx.x == 0) *flag = (mask == 0ULL) ? 1 : 0;
    }
    int id = blockIdx.x * blockDim.x + threadIdx.x;
    if(id < N) deg[id] = 0;
    if(id < X4){
        const float4 v = *(const float4*)&x[(size_t)id * 4];
        ushort4v o;
        o[0] = f2bf(v.x); o[1] = f2bf(v.y); o[2] = f2bf(v.z); o[3] = f2bf(v.w);
        *(ushort4v*)&xbf[(size_t)id * 4] = o;
        return;
    }
    id -= X4;
    if(id < 16 * 128){ emit_wa(W1, as1, ad1, Wa1, 128, 64, id); return; }
    id -= 16 * 128;
    if(id < 16 * 64){ emit_wa(W2, as2, ad2, Wa2, 64, 64, id); return; }
    id -= 16 * 64;
    if(id < 16 * 64){ emit_wa(W3, as3, ad3, Wa3, 64, 40, id); return; }
    id -= 16 * 64;
    if(id < 64 * 512){ emit_wc(W1, Wc1, 128, 64, id); return; }
    id -= 64 * 512;
    if(id < 64 * 256){ emit_wc(W2, Wc2, 64, 64, id); return; }
    id -= 64 * 256;
    if(id < 48 * 256){ emit_wc(W3, Wc3, 64, 40, id); }
}

// ---------------- histogram off the raw edge buffer ----------------
__global__ void hist_kernel(const void* __restrict__ e, const int* __restrict__ flag,
                            int* __restrict__ deg, int E){
    const int i = blockIdx.x * blockDim.x + threadIdx.x;
    if(i < E){
        const int d = (*flag) ? (int)((const long long*)e)[E + i] : ((const int*)e)[E + i];
        atomicAdd(&deg[d], 1);
    }
}

// ---------------- CSR build (hierarchical scan) ----------------
__global__ __launch_bounds__(512) void scan1_kernel(const int* __restrict__ deg,
                                                    int* __restrict__ excl,
                                                    int* __restrict__ bsum, int n){
    __shared__ int sh[512];
    const int t = threadIdx.x;
    const int gid = blockIdx.x * 512 + t;
    const int v = (gid < n) ? deg[gid] : 0;
    sh[t] = v;
    __syncthreads();
    for(int off = 1; off < 512; off <<= 1){
        const int add = (t >= off) ? sh[t - off] : 0;
        __syncthreads();
        sh[t] += add;
        __syncthreads();
    }
    if(gid < n) excl[gid] = sh[t] - v;
    if(t == 511) bsum[blockIdx.x] = sh[511];
}

__global__ __launch_bounds__(128) void scan2_kernel(int* __restrict__ bsum, int nb){
    __shared__ int sh[128];
    const int t = threadIdx.x;
    const int v = (t < nb) ? bsum[t] : 0;
    sh[t] = v;
    __syncthreads();
    for(int off = 1; off < 128; off <<= 1){
        const int add = (t >= off) ? sh[t - off] : 0;
        __syncthreads();
        sh[t] += add;
        __syncthreads();
    }
    if(t < nb) bsum[t] = sh[t] - v;
}

__global__ void scan3_kernel(const int* __restrict__ excl, const int* __restrict__ bsum,
                             int* __restrict__ row_ptr, int* __restrict__ cursor,
                             int n, int E){
    const int gid = blockIdx.x * blockDim.x + threadIdx.x;
    if(gid < n){
        const int r = excl[gid] + bsum[gid >> 9];
        row_ptr[gid] = r;
        cursor[gid] = r;
    }
    if(gid == 0) row_ptr[n] = E;
}

__global__ void scatter_kernel(const void* __restrict__ e, const int* __restrict__ flag,
                               int* __restrict__ cursor, int* __restrict__ col, int E){
    const int i = blockIdx.x * blockDim.x + threadIdx.x;
    if(i < E){
        int s, d;
        if(*flag){ s = (int)((const long long*)e)[i]; d = (int)((const long long*)e)[E + i]; }
        else     { s = ((const int*)e)[i];            d = ((const int*)e)[E + i]; }
        const int pos = atomicAdd(&cursor[d], 1);
        col[pos] = s;
    }
}

// ---------------- alpha GEMM (layer 1 only): ea/ed = exp(A @ Wa) ----------------
template<int K>
__global__ __launch_bounds__(256) void agemm_kernel(const unsigned short* __restrict__ A,
                                                    const unsigned short* __restrict__ Wa,
                                                    float* __restrict__ ea, float* __restrict__ ed,
                                                    int M){
    const int lane = threadIdx.x & 63;
    const int wave = threadIdx.x >> 6;
    const int quad = lane >> 4;
    const int l16 = lane & 15;
    const int bm = blockIdx.x * 64;
    const int m = min(bm + wave * 16 + l16, M - 1);
    f32x4 acc = {0,0,0,0};
    #pragma unroll
    for(int k0 = 0; k0 < K; k0 += 32){
        const short8v a = *(const short8v*)&A[(size_t)m * K + k0 + quad * 8];
        const short8v b = *(const short8v*)&Wa[(size_t)l16 * K + k0 + quad * 8];
        acc = __builtin_amdgcn_mfma_f32_16x16x32_bf16(a, b, acc, 0, 0, 0);
    }
    if(l16 < 8){
        const int h = l16 & 3;
        float* dst = (l16 < 4) ? ea : ed;
        const int rbase = bm + wave * 16 + quad * 4;
        #pragma unroll
        for(int r = 0; r < 4; r++){
            const int row = rbase + r;
            if(row < M){
                const float v = acc[r];
                *(f32x2*)&dst[(size_t)row * 8 + 2 * h] = (f32x2){__expf(v), __expf(NEG_SLOPE * v)};
            }
        }
    }
}

// ---------------- edge-parallel RAW gather: g[n][h][K] = (sum_e w_h * X[s]) / dnm_h
// Block 256 = 4 waves, 1 node/wave (proven scheduling shape, no barrier).
// Phase A: lane e owns edge e -- coalesced col load, independent ea loads, w[4] + s
//          stashed in wave-private LDS (within-wave lgkmcnt ordering, no barrier).
// Phase B (K=128): 64 lanes x 4B cover the 256B row; lane owns 2 channels x 4 heads.
// Phase B (K=64):  two edges in flight (lanes 0-31 / 32-63), fold with shfl_xor(32).
// Epilogue: normalize per head, write bf16 g in round-0 layout (pgemm-compatible).
template<int K>
__global__ __launch_bounds__(256) void gatherg_kernel(const unsigned short* __restrict__ X,
                                                      const int* __restrict__ row_ptr,
                                                      const int* __restrict__ col,
                                                      const float* __restrict__ ea,
                                                      const float* __restrict__ ed,
                                                      unsigned short* __restrict__ g){
    __shared__ int   ls[4][64];
    __shared__ float lw[4][64][4];
    const int lane = threadIdx.x & 63;
    const int wave = threadIdx.x >> 6;
    const int n    = blockIdx.x * 4 + wave;
    const int rs = row_ptr[n], re = row_ptr[n + 1];
    const int T = re - rs + 1;                    // edges + virtual self loop
    const float4 edA = *(const float4*)&ed[(size_t)n * 8];
    const float4 edB = *(const float4*)&ed[(size_t)n * 8 + 4];

    f32x2 acc[4];
    #pragma unroll
    for(int h = 0; h < 4; h++) acc[h] = (f32x2){0.f, 0.f};
    float d0 = 0.f, d1 = 0.f, d2 = 0.f, d3 = 0.f;

    const int c2 = (K == 128) ? (lane * 2) : ((lane & 31) * 2);
    const int eo = lane >> 5;

    for(int base = 0; base < T; base += 64){
        const int ecnt = min(T - base, 64);
        if(lane < ecnt){
            const int e = rs + base + lane;
            const int s = (e < re) ? col[e] : n;  // e==re => self loop
            const float4 eaA = *(const float4*)&ea[(size_t)s * 8];
            const float4 eaB = *(const float4*)&ea[(size_t)s * 8 + 4];
            const float w0 = fmaxf(eaA.x * edA.x, eaA.y * edA.y);
            const float w1 = fmaxf(eaA.z * edA.z, eaA.w * edA.w);
            const float w2 = fmaxf(eaB.x * edB.x, eaB.y * edB.y);
            const float w3 = fmaxf(eaB.z * edB.z, eaB.w * edB.w);
            d0 += w0; d1 += w1; d2 += w2; d3 += w3;
            ls[wave][lane] = s;
            *(f32x4*)&lw[wave][lane][0] = (f32x4){w0, w1, w2, w3};
        }
        if constexpr(K == 128){
            auto body = [&](int e){
                const int s = ls[wave][e];                      // LDS broadcast
                const f32x4 w4 = *(const f32x4*)&lw[wave][e][0];
                const unsigned u = *(const unsigned*)&X[(size_t)s * K + c2];
                const f32x2 v = {__uint_as_float(u << 16), __uint_as_float(u & 0xffff0000u)};
                acc[0] += (f32x2){w4[0], w4[0]} * v;
                acc[1] += (f32x2){w4[1], w4[1]} * v;
                acc[2] += (f32x2){w4[2], w4[2]} * v;
                acc[3] += (f32x2){w4[3], w4[3]} * v;
            };
            int e = 0;
            for(; e + 4 <= ecnt; e += 4){ body(e); body(e + 1); body(e + 2); body(e + 3); }
            for(; e < ecnt; e++) body(e);
        } else {
            auto body = [&](int p){                             // pair: edges p, p+1
                const int e = p + eo;
                if(e < ecnt){
                    const int s = ls[wave][e];                  // 2-way LDS (free)
                    const f32x4 w4 = *(const f32x4*)&lw[wave][e][0];
                    const unsigned u = *(const unsigned*)&X[(size_t)s * K + c2];
                    const f32x2 v = {__uint_as_float(u << 16), __uint_as_float(u & 0xffff0000u)};
                    acc[0] += (f32x2){w4[0], w4[0]} * v;
                    acc[1] += (f32x2){w4[1], w4[1]} * v;
                    acc[2] += (f32x2){w4[2], w4[2]} * v;
                    acc[3] += (f32x2){w4[3], w4[3]} * v;
                }
            };
            int p = 0;
            for(; p + 8 <= ecnt; p += 8){ body(p); body(p + 2); body(p + 4); body(p + 6); }
            for(; p < ecnt; p += 2) body(p);
        }
    }

    // denominators: reduce per-lane partials over all 64 lanes
    #pragma unroll
    for(int msk = 1; msk < 64; msk <<= 1){
        d0 += __shfl_xor(d0, msk); d1 += __shfl_xor(d1, msk);
        d2 += __shfl_xor(d2, msk); d3 += __shfl_xor(d3, msk);
    }
    if constexpr(K == 64){
        // fold the two edge-halves (same channel mapping in both)
        #pragma unroll
        for(int h = 0; h < 4; h++){
            acc[h][0] += __shfl_xor(acc[h][0], 32);
            acc[h][1] += __shfl_xor(acc[h][1], 32);
        }
    }
    const float invs[4] = {1.f / d0, 1.f / d1, 1.f / d2, 1.f / d3};
    if(K == 128 || lane < 32){
        #pragma unroll
        for(int h = 0; h < 4; h++){
            const unsigned lo = f2bf(acc[h][0] * invs[h]);
            const unsigned hi = f2bf(acc[h][1] * invs[h]);
            *(unsigned*)&g[(size_t)n * (4 * K) + h * K + c2] = lo | (hi << 16);
        }
    }
}

// ---------------- post-aggregation GEMM (+fused next-layer alpha) ----------------
// out = g[n,KC] @ Wcat + bias, relu -> h bf16 (or FINAL log_softmax, fp32).
// ALPHA: each wave round-trips its own 16 bf16 h-rows through LDS (no block
// barrier -- wave-private tile) and runs 2 MFMAs vs Wa (K=64) to emit the next
// layer's pre-exponentiated ea/ed.
template<int KC, int NC, bool FINAL, bool ALPHA>
__global__ __launch_bounds__(256) void pgemm_kernel(const unsigned short* __restrict__ A,
                                                    const unsigned short* __restrict__ Bt,
                                                    const float* __restrict__ bias,
                                                    void* __restrict__ outv,
                                                    const unsigned short* __restrict__ Wa,
                                                    float* __restrict__ ea,
                                                    float* __restrict__ ed,
                                                    int M){
    constexpr int NT = (NC + 15) / 16;   // 4 (NC=64) or 3 (NC=40)
    __shared__ unsigned short lh[ALPHA ? 4 : 1][16][72];   // 72-stride: 16B-aligned rows, 2-way banks
    const int lane = threadIdx.x & 63;
    const int wave = threadIdx.x >> 6;
    const int quad = lane >> 4;
    const int l16 = lane & 15;
    const int bm = blockIdx.x * 64;
    const int m = min(bm + wave * 16 + l16, M - 1);
    const size_t arow = (size_t)m * KC;

    f32x4 acc[NT];
    #pragma unroll
    for(int t = 0; t < NT; t++) acc[t] = (f32x4){0,0,0,0};

    for(int k0 = 0; k0 < KC; k0 += 32){
        const short8v a = *(const short8v*)&A[arow + k0 + quad * 8];
        #pragma unroll
        for(int t = 0; t < NT; t++){
            const short8v b = *(const short8v*)&Bt[(size_t)(t * 16 + l16) * KC + k0 + quad * 8];
            acc[t] = __builtin_amdgcn_mfma_f32_16x16x32_bf16(a, b, acc[t], 0, 0, 0);
        }
    }
    const int rbase = bm + wave * 16 + quad * 4;
    if(!FINAL){
        unsigned short* out = (unsigned short*)outv;
        #pragma unroll
        for(int t = 0; t < NT; t++){
            const int c = t * 16 + l16;
            #pragma unroll
            for(int r = 0; r < 4; r++){
                const unsigned short hb = f2bf(fmaxf(acc[t][r] + bias[c], 0.f));
                const int row = rbase + r;
                if(row < M) out[(size_t)row * NC + c] = hb;
                if constexpr(ALPHA) lh[wave][quad * 4 + r][c] = hb;
            }
        }
        if constexpr(ALPHA){
            // wave-private LDS tile: within-wave lgkmcnt ordering suffices (no barrier)
            f32x4 a4 = {0, 0, 0, 0};
            #pragma unroll
            for(int k0 = 0; k0 < 64; k0 += 32){
                const short8v a = *(const short8v*)&lh[wave][l16][k0 + quad * 8];
                const short8v b = *(const short8v*)&Wa[(size_t)l16 * 64 + k0 + quad * 8];
                a4 = __builtin_amdgcn_mfma_f32_16x16x32_bf16(a, b, a4, 0, 0, 0);
            }
            if(l16 < 8){
                const int h = l16 & 3;
                float* dst = (l16 < 4) ? ea : ed;
                #pragma unroll
                for(int r = 0; r < 4; r++){
                    const int row = rbase + r;
                    if(row < M){
                        const float v = a4[r];
                        *(f32x2*)&dst[(size_t)row * 8 + 2 * h] = (f32x2){__expf(v), __expf(NEG_SLOPE * v)};
                    }
                }
            }
        }
    } else {
        float* out = (float*)outv;
        float o[NT][4];
        #pragma unroll
        for(int t = 0; t < NT; t++){
            const int c = t * 16 + l16;
            const bool valid = c < 40;
            const float bc = valid ? bias[c] : 0.f;
            #pragma unroll
            for(int r = 0; r < 4; r++)
                o[t][r] = valid ? fmaxf(acc[t][r] + bc, 0.f) : -INFINITY;
        }
        #pragma unroll
        for(int r = 0; r < 4; r++){
            float mx = o[0][r];
            #pragma unroll
            for(int t = 1; t < NT; t++) mx = fmaxf(mx, o[t][r]);
            #pragma unroll
            for(int off = 1; off < 16; off <<= 1) mx = fmaxf(mx, __shfl_xor(mx, off));
            float se = 0.f;
            #pragma unroll
            for(int t = 0; t < NT; t++) se += (o[t][r] > -INFINITY) ? __expf(o[t][r] - mx) : 0.f;
            #pragma unroll
            for(int off = 1; off < 16; off <<= 1) se += __shfl_xor(se, off);
            const float lz = mx + logf(se);
            const int row = rbase + r;
            if(row < M){
                #pragma unroll
                for(int t = 0; t < NT; t++){
                    const int c = t * 16 + l16;
                    if(c < 40) out[(size_t)row * 40 + c] = o[t][r] - lz;
                }
            }
        }
    }
}

// ---------------- driver ----------------
extern "C" void kernel_launch(void* const* d_in, const int* in_sizes, int n_in,
                              void* d_out, int out_size, void* d_ws, size_t ws_size,
                              hipStream_t stream){
    const int N = NNODES;
    const int E = in_sizes[1] / 2;

    const float* x   = (const float*)d_in[0];
    const float* W1  = (const float*)d_in[2];
    const float* as1 = (const float*)d_in[3];
    const float* ad1 = (const float*)d_in[4];
    const float* b1  = (const float*)d_in[5];
    const float* W2  = (const float*)d_in[6];
    const float* as2 = (const float*)d_in[7];
    const float* ad2 = (const float*)d_in[8];
    const float* b2  = (const float*)d_in[9];
    const float* W3  = (const float*)d_in[10];
    const float* as3 = (const float*)d_in[11];
    const float* ad3 = (const float*)d_in[12];
    const float* b3  = (const float*)d_in[13];

    char* ws = (char*)d_ws;
    size_t off = 0;
    auto alloc = [&](size_t bytes) -> void* {
        void* p = ws + off;
        off = (off + bytes + 255) & ~(size_t)255;
        return p;
    };
    int*   flag    = (int*)  alloc(4);
    int*   row_ptr = (int*)  alloc((size_t)(N + 1) * 4);
    int*   colv    = (int*)  alloc((size_t)E * 4);
    int*   cursor  = (int*)  alloc((size_t)N * 4);
    int*   deg     = (int*)  alloc((size_t)N * 4);
    int*   excl    = (int*)  alloc((size_t)N * 4);
    int*   bsum    = (int*)  alloc(128 * 4);
    unsigned short* xbf = (unsigned short*)alloc((size_t)N * 128 * 2);
    unsigned short* Wa1 = (unsigned short*)alloc(16 * 128 * 2);
    unsigned short* Wa2 = (unsigned short*)alloc(16 * 64 * 2);
    unsigned short* Wa3 = (unsigned short*)alloc(16 * 64 * 2);
    unsigned short* Wc1 = (unsigned short*)alloc((size_t)64 * 512 * 2);
    unsigned short* Wc2 = (unsigned short*)alloc((size_t)64 * 256 * 2);
    unsigned short* Wc3 = (unsigned short*)alloc((size_t)48 * 256 * 2);
    float* eav     = (float*)alloc((size_t)N * 8 * 4);
    float* edv     = (float*)alloc((size_t)N * 8 * 4);
    unsigned short* g   = (unsigned short*)alloc((size_t)N * 512 * 2);
    unsigned short* h1  = (unsigned short*)alloc((size_t)N * 64 * 2);
    unsigned short* h2  = (unsigned short*)alloc((size_t)N * 64 * 2);
    (void)ws_size;

    const void* eraw = d_in[1];

    const int X4 = N * 128 / 4;
    const int prepTotal = X4 + 16*128 + 16*64 + 16*64 + 64*512 + 64*256 + 48*256;
    initprep_kernel<<<(prepTotal + 255) / 256, 256, 0, stream>>>(
        (const unsigned long long*)eraw, flag, deg, N, x, xbf, X4,
        W1, as1, ad1, W2, as2, ad2, W3, as3, ad3,
        Wa1, Wa2, Wa3, Wc1, Wc2, Wc3);

    hist_kernel<<<(E + 255) / 256, 256, 0, stream>>>(eraw, flag, deg, E);
    const int nbScan = (N + 511) / 512;
    scan1_kernel<<<nbScan, 512, 0, stream>>>(deg, excl, bsum, N);
    scan2_kernel<<<1, 128, 0, stream>>>(bsum, nbScan);
    scan3_kernel<<<(N + 255) / 256, 256, 0, stream>>>(excl, bsum, row_ptr, cursor, N, E);
    scatter_kernel<<<(E + 255) / 256, 256, 0, stream>>>(eraw, flag, cursor, colv, E);

    const int nodeBlocks = N / 4;              // 12500
    const int mBlocks = (N + 63) / 64;         // 782

    // layer 1: features x (K=128); alpha for layer 2 fused into pgemm1
    agemm_kernel<128><<<mBlocks, 256, 0, stream>>>(xbf, Wa1, eav, edv, N);
    gatherg_kernel<128><<<nodeBlocks, 256, 0, stream>>>(xbf, row_ptr, colv, eav, edv, g);
    pgemm_kernel<512, 64, false, true><<<mBlocks, 256, 0, stream>>>(g, Wc1, b1, h1, Wa2, eav, edv, N);

    // layer 2: features h1 (K=64); alpha for layer 3 fused into pgemm2
    gatherg_kernel<64><<<nodeBlocks, 256, 0, stream>>>(h1, row_ptr, colv, eav, edv, g);
    pgemm_kernel<256, 64, false, true><<<mBlocks, 256, 0, stream>>>(g, Wc2, b2, h2, Wa3, eav, edv, N);

    // layer 3: features h2 (K=64) + fused log_softmax
    gatherg_kernel<64><<<nodeBlocks, 256, 0, stream>>>(h2, row_ptr, colv, eav, edv, g);
    pgemm_kernel<256, 40, true, false><<<mBlocks, 256, 0, stream>>>(g, Wc3, b3, d_out, nullptr, nullptr, nullptr, N);
}